// Round 7
// baseline (247.291 us; speedup 1.0000x reference)
//
#include <hip/hip_runtime.h>
#include <hip/hip_bf16.h>
#include <stdint.h>

typedef unsigned short u16;
typedef __bf16 bf16x8 __attribute__((ext_vector_type(8)));
typedef float f32x4 __attribute__((ext_vector_type(4)));
typedef float f32x16 __attribute__((ext_vector_type(16)));

#define D_MODEL 1024
#define SEQ     2048
#define NB      2
#define NH      16
#define HD      64
#define M_TOT   (NB*SEQ)        // 4096
// attention scale folded with log2(e): scores come out in log2 domain
#define QSCALE  (0.125f * 1.44269504088896f)
#define DEFER_THR 8.0f          // log2-domain defer-max threshold (P <= 2^8)

__device__ __forceinline__ u16 f2bf(float f) {
  union { __bf16 b; u16 u; } cv; cv.b = (__bf16)f; return cv.u;
}
__device__ __forceinline__ float exp2_fast(float x) {
  return __builtin_amdgcn_exp2f(x);
}

// async global->LDS, 16B per lane. lds_dst must be wave-uniform (HW adds lane*16).
__device__ __forceinline__ void async_copy16(void* lds_dst, const void* gsrc) {
  __builtin_amdgcn_global_load_lds(
      (const __attribute__((address_space(1))) unsigned int*)gsrc,
      (__attribute__((address_space(3))) unsigned int*)lds_dst, 16, 0, 0);
}

// ---------------- fused f32 -> bf16 convert for Z + 4 weights ----------------
__global__ void cvt_all(const float* __restrict__ Z,  const float* __restrict__ Wq,
                        const float* __restrict__ Wk, const float* __restrict__ Wv,
                        const float* __restrict__ Wo,
                        u16* __restrict__ Zb,  u16* __restrict__ Wqb,
                        u16* __restrict__ Wkb, u16* __restrict__ Wvb,
                        u16* __restrict__ Wob)
{
  int i = blockIdx.x * 256 + threadIdx.x;    // 0 .. 2^21-1
  const float* src; u16* dst; int off;
  if (i < (1 << 20)) { src = Z; dst = Zb; off = i; }
  else {
    int j = i - (1 << 20);
    int seg = j >> 18; off = j & ((1 << 18) - 1);
    src = (seg == 0) ? Wq : (seg == 1) ? Wk : (seg == 2) ? Wv : Wo;
    dst = (seg == 0) ? Wqb : (seg == 1) ? Wkb : (seg == 2) ? Wvb : Wob;
  }
  float4 v = reinterpret_cast<const float4*>(src)[off];
  ushort4 o;
  o.x = f2bf(v.x); o.y = f2bf(v.y); o.z = f2bf(v.z); o.w = f2bf(v.w);
  reinterpret_cast<ushort4*>(dst)[off] = o;
}

// ---------------- 256x256 GEMM: C = (A @ Bt^T + bias) * oscl ----------------
// 512 threads = 8 waves (2M x 4N), per-wave 128x64 output, BK=64, double-buffered
// LDS (128KB dynamic). Proven sync protocol: counted vmcnt -> barrier -> compute
// -> barrier -> stage(t+2). LDS slot swizzle: LDS[row][sl] holds global k-chunk
// sl ^ (row&7); read slot = (lhi | ks*4) ^ (l15&7).
// TRANSV && z==2: swapped-operand MFMA, writes Vt[(b*NH+h)*HD+d][s] coalesced.
template<int F32OUT, int TRANSV>
__global__ __launch_bounds__(512, 2)
void gemm256(const u16* __restrict__ A,
             const u16* __restrict__ B0, const u16* __restrict__ B1, const u16* __restrict__ B2,
             const float* __restrict__ bias0, const float* __restrict__ bias1, const float* __restrict__ bias2,
             void* __restrict__ C0, void* __restrict__ C1, void* __restrict__ C2,
             float s0f, float s1f, float s2f,
             int M, int N, int K)
{
  (void)M;
  const int z = blockIdx.z;
  const u16* Bt = (z == 0) ? B0 : ((z == 1) ? B1 : B2);
  const float* bias = (z == 0) ? bias0 : ((z == 1) ? bias1 : bias2);
  void* Cout = (z == 0) ? C0 : ((z == 1) ? C1 : C2);
  const float oscl = (z == 0) ? s0f : ((z == 1) ? s1f : s2f);
  const bool vswap = TRANSV && (z == 2);

  extern __shared__ u16 smem[];          // [2][256*64] A then [2][256*64] B
  char* La = (char*)smem;                // 64KB
  char* Lb = (char*)smem + 65536;        // 64KB

  const int tid = threadIdx.x;
  const int w = tid >> 6, lane = tid & 63;
  const int l15 = lane & 15, lhi = lane >> 4;
  const int m0 = blockIdx.y * 256, n0 = blockIdx.x * 256;
  const int wm = w >> 2, wn = w & 3;     // 2 x 4 wave grid

  f32x4 acc[8][4] = {};                  // 128 VGPRs

  // precomputed staging offsets (elements) and LDS byte bases
  int aoff[4], boff[4];
  #pragma unroll
  for (int i = 0; i < 4; ++i) {
    const int c = i*512 + tid;           // chunk 0..2047
    const int row = c >> 3;              // 0..255
    const int sl  = c & 7;               // LDS slot
    const int sg  = sl ^ (row & 7);      // inverse-swizzled global k-chunk
    aoff[i] = (m0 + row) * K + sg*8;
    boff[i] = (n0 + row) * K + sg*8;
  }
  const int ldsoff0 = (0*512 + w*64)*16, ldsoff1 = (1*512 + w*64)*16,
            ldsoff2 = (2*512 + w*64)*16, ldsoff3 = (3*512 + w*64)*16;

  auto stage = [&](int buf, int kt) {
    const int ko = kt << 6;
    const int bb = buf * 32768;
    async_copy16(La + bb + ldsoff0, A  + (size_t)(aoff[0] + ko));
    async_copy16(Lb + bb + ldsoff0, Bt + (size_t)(boff[0] + ko));
    async_copy16(La + bb + ldsoff1, A  + (size_t)(aoff[1] + ko));
    async_copy16(Lb + bb + ldsoff1, Bt + (size_t)(boff[1] + ko));
    async_copy16(La + bb + ldsoff2, A  + (size_t)(aoff[2] + ko));
    async_copy16(Lb + bb + ldsoff2, Bt + (size_t)(boff[2] + ko));
    async_copy16(La + bb + ldsoff3, A  + (size_t)(aoff[3] + ko));
    async_copy16(Lb + bb + ldsoff3, Bt + (size_t)(boff[3] + ko));
  };

  const int s0 = lhi ^ (l15 & 7);                       // read slot, ks=0
  const int abase = (wm*128 + l15)*128 + s0*16;         // byte in A-buf
  const int bbase = (wn*64  + l15)*128 + s0*16;         // byte in B-buf

  auto compute = [&](int buf) {
    const int bb = buf * 32768;
    #pragma unroll
    for (int ks = 0; ks < 2; ++ks) {
      const int pa = bb + (abase ^ (ks << 6));          // slot XOR 4 == byte XOR 64
      const int pb = bb + (bbase ^ (ks << 6));
      bf16x8 bf[4];
      #pragma unroll
      for (int ni = 0; ni < 4; ++ni)
        bf[ni] = *reinterpret_cast<const bf16x8*>(Lb + pb + ni*2048);
      #pragma unroll
      for (int mi = 0; mi < 8; ++mi) {
        bf16x8 af = *reinterpret_cast<const bf16x8*>(La + pa + mi*2048);
        if (vswap) {
          #pragma unroll
          for (int ni = 0; ni < 4; ++ni)
            acc[mi][ni] = __builtin_amdgcn_mfma_f32_16x16x32_bf16(bf[ni], af, acc[mi][ni], 0, 0, 0);
        } else {
          #pragma unroll
          for (int ni = 0; ni < 4; ++ni)
            acc[mi][ni] = __builtin_amdgcn_mfma_f32_16x16x32_bf16(af, bf[ni], acc[mi][ni], 0, 0, 0);
        }
      }
    }
  };

  const int nt = K >> 6;                 // 16 K-tiles
  stage(0, 0);
  stage(1, 1);
  for (int t = 0; t < nt; ++t) {
    const int cb = t & 1;
    if (t + 1 < nt) { asm volatile("s_waitcnt vmcnt(8)" ::: "memory"); }
    else            { asm volatile("s_waitcnt vmcnt(0)" ::: "memory"); }
    __builtin_amdgcn_sched_barrier(0);
    __builtin_amdgcn_s_barrier();        // tile t resident for all waves
    __builtin_amdgcn_sched_barrier(0);
    compute(cb);
    __builtin_amdgcn_sched_barrier(0);
    __builtin_amdgcn_s_barrier();        // all waves done with buf cb
    if (t + 2 < nt) stage(cb, t + 2);
  }

  if (vswap) {
    // acc[mi][ni] = C^T frag: d = n0+wn*64+ni*16+lhi*4+r, s = m0+wm*128+mi*16+l15
    #pragma unroll
    for (int mi = 0; mi < 8; ++mi) {
      const int sglob = m0 + wm*128 + mi*16 + l15;
      const int b2 = sglob >> 11, s = sglob & (SEQ - 1);
      #pragma unroll
      for (int ni = 0; ni < 4; ++ni) {
        #pragma unroll
        for (int r = 0; r < 4; ++r) {
          const int dglob = n0 + wn*64 + ni*16 + (lhi << 2) + r;
          const int hh = dglob >> 6, dd = dglob & 63;
          const float v = acc[mi][ni][r] + bias[dglob];
          reinterpret_cast<u16*>(Cout)[((size_t)(b2*NH + hh)*HD + dd)*SEQ + s] = f2bf(v);
        }
      }
    }
  } else {
    // C/D layout col=lane&15, row=(lane>>4)*4+reg
    #pragma unroll
    for (int mi = 0; mi < 8; ++mi) {
      const int rowb = m0 + wm*128 + mi*16 + (lhi << 2);
      #pragma unroll
      for (int ni = 0; ni < 4; ++ni) {
        const int col = n0 + wn*64 + ni*16 + l15;
        const float bb = bias[col];
        #pragma unroll
        for (int r = 0; r < 4; ++r) {
          const float v = (acc[mi][ni][r] + bb) * oscl;
          if (F32OUT)
            reinterpret_cast<float*>(Cout)[(size_t)(rowb + r) * N + col] = v;
          else
            reinterpret_cast<u16*>(Cout)[(size_t)(rowb + r) * N + col] = f2bf(v);
        }
      }
    }
  }
}

// ---------------- fused flash attention, swapped 32x32 structure ----------------
// (unchanged from round 6 — proven)
__global__ __launch_bounds__(256, 2)
void attn32(const u16* __restrict__ Qb, const u16* __restrict__ Kb,
            const u16* __restrict__ Vt, u16* __restrict__ Ob)
{
  __shared__ u16 vt[3][64*64];   // [d][8 slots of 8 keys]
  __shared__ u16 kt[3][64*64];   // [key][8 slots of 8 d]

  const int tid = threadIdx.x;
  const int w = tid >> 6, lane = tid & 63;
  const int l31 = lane & 31, hi = lane >> 5;
  const int bh = blockIdx.y, b = bh >> 4, h = bh & 15;
  const int qrow = blockIdx.x * 128 + w * 32 + l31;

  bf16x8 qf[4];
  {
    const u16* qp = Qb + (size_t)(b*SEQ + qrow) * D_MODEL + h*HD + hi*8;
    #pragma unroll
    for (int kc = 0; kc < 4; ++kc)
      qf[kc] = *reinterpret_cast<const bf16x8*>(qp + kc*16);
  }

  const u16* Vtg = Vt + (size_t)bh * HD * SEQ;            // [64 d][2048 s]
  const u16* Kg  = Kb + (size_t)(b*SEQ) * D_MODEL + h*HD; // rows [s][64 d]

  float mrun = -1e30f, lrun = 0.f;
  f32x16 o0 = {}, o1 = {};

  auto stageKV = [&](int buf, int kv0) {
    #pragma unroll
    for (int i = 0; i < 2; ++i) {
      const int c = i*256 + tid;
      const int d = c >> 3;
      const int sl = c & 7;
      const int sg = sl ^ (d & 7);
      async_copy16((char*)vt[buf] + (size_t)(i*256 + w*64)*16,
                   (const char*)(Vtg + (size_t)d*SEQ + kv0 + sg*8));
    }
    #pragma unroll
    for (int i = 0; i < 2; ++i) {
      const int c = i*256 + tid;
      const int key = c >> 3;
      const int sl = c & 7;
      const int sg = sl ^ (key & 7);
      async_copy16((char*)kt[buf] + (size_t)(i*256 + w*64)*16,
                   (const char*)(Kg + (size_t)(kv0 + key)*D_MODEL + sg*8));
    }
  };

  const int nt = SEQ / 64;   // 32 tiles
  stageKV(0, 0);
  stageKV(1, 64);

  for (int t = 0; t < nt; ++t) {
    const int cb = t % 3;
    if (t + 2 < nt) stageKV((t + 2) % 3, (t + 2) * 64);
    if (t + 2 < nt)      { asm volatile("s_waitcnt vmcnt(8)" ::: "memory"); }
    else if (t + 1 < nt) { asm volatile("s_waitcnt vmcnt(4)" ::: "memory"); }
    else                 { asm volatile("s_waitcnt vmcnt(0)" ::: "memory"); }
    __builtin_amdgcn_sched_barrier(0);
    __builtin_amdgcn_s_barrier();
    __builtin_amdgcn_sched_barrier(0);

    f32x16 s0 = {}, s1 = {};
    {
      const char* kbp = (const char*)kt[cb];
      #pragma unroll
      for (int kc = 0; kc < 4; ++kc) {
        const int sw = (kc*2 + hi) ^ (l31 & 7);
        bf16x8 ka0 = *reinterpret_cast<const bf16x8*>(kbp + (size_t)(l31*8 + sw)*16);
        s0 = __builtin_amdgcn_mfma_f32_32x32x16_bf16(ka0, qf[kc], s0, 0, 0, 0);
        bf16x8 ka1 = *reinterpret_cast<const bf16x8*>(kbp + (size_t)((l31+32)*8 + sw)*16);
        s1 = __builtin_amdgcn_mfma_f32_32x32x16_bf16(ka1, qf[kc], s1, 0, 0, 0);
      }
    }

    float tmax = s0[0];
    #pragma unroll
    for (int r = 1; r < 16; ++r) tmax = fmaxf(tmax, s0[r]);
    #pragma unroll
    for (int r = 0; r < 16; ++r) tmax = fmaxf(tmax, s1[r]);
    tmax = fmaxf(tmax, __shfl_xor(tmax, 32));
    if (!__all(tmax - mrun <= DEFER_THR)) {
      const float mnew = fmaxf(mrun, tmax);
      const float a = exp2_fast(mrun - mnew);
      lrun *= a;
      #pragma unroll
      for (int r = 0; r < 16; ++r) { o0[r] *= a; o1[r] *= a; }
      mrun = mnew;
    }
    float rs = 0.f;
    #pragma unroll
    for (int r = 0; r < 16; ++r) { s0[r] = exp2_fast(s0[r] - mrun); rs += s0[r]; }
    #pragma unroll
    for (int r = 0; r < 16; ++r) { s1[r] = exp2_fast(s1[r] - mrun); rs += s1[r]; }
    rs += __shfl_xor(rs, 32);
    lrun += rs;

    unsigned pwA[2][8];
    #pragma unroll
    for (int a4 = 0; a4 < 4; ++a4)
      #pragma unroll
      for (int zz = 0; zz < 2; ++zz) {
        pwA[0][a4*2+zz] = (unsigned)f2bf(s0[4*a4+2*zz]) | ((unsigned)f2bf(s0[4*a4+2*zz+1]) << 16);
        pwA[1][a4*2+zz] = (unsigned)f2bf(s1[4*a4+2*zz]) | ((unsigned)f2bf(s1[4*a4+2*zz+1]) << 16);
      }

    const char* vb = (const char*)vt[cb];
    #pragma unroll
    for (int ks = 0; ks < 4; ++ks) {
      const int kb = ks >> 1, sm = ks & 1;
      unsigned keep0 = hi ? pwA[kb][(2*sm+1)*2+0] : pwA[kb][(2*sm)*2+0];
      unsigned keep1 = hi ? pwA[kb][(2*sm+1)*2+1] : pwA[kb][(2*sm)*2+1];
      unsigned send0 = hi ? pwA[kb][(2*sm)*2+0]   : pwA[kb][(2*sm+1)*2+0];
      unsigned send1 = hi ? pwA[kb][(2*sm)*2+1]   : pwA[kb][(2*sm+1)*2+1];
      unsigned recv0 = (unsigned)__shfl_xor((int)send0, 32);
      unsigned recv1 = (unsigned)__shfl_xor((int)send1, 32);
      union { bf16x8 f; unsigned u[4]; } pf;
      pf.u[0] = hi ? recv0 : keep0;
      pf.u[1] = hi ? recv1 : keep1;
      pf.u[2] = hi ? keep0 : recv0;
      pf.u[3] = hi ? keep1 : recv1;

      const int slg = ks*2 + hi;
      const int sw  = slg ^ (l31 & 7);
      bf16x8 va0 = *reinterpret_cast<const bf16x8*>(vb + (size_t)(l31*8 + sw)*16);
      bf16x8 va1 = *reinterpret_cast<const bf16x8*>(vb + (size_t)((l31+32)*8 + sw)*16);

      o0 = __builtin_amdgcn_mfma_f32_32x32x16_bf16(va0, pf.f, o0, 0, 0, 0);
      o1 = __builtin_amdgcn_mfma_f32_32x32x16_bf16(va1, pf.f, o1, 0, 0, 0);
    }

    __builtin_amdgcn_sched_barrier(0);
    __builtin_amdgcn_s_barrier();
  }

  const float inv = 1.0f / lrun;
  u16* op = Ob + (size_t)(b*SEQ + qrow) * D_MODEL + h*HD;
  #pragma unroll
  for (int a4 = 0; a4 < 4; ++a4) {
    ushort4 v0, v1;
    v0.x = f2bf(o0[4*a4+0]*inv); v0.y = f2bf(o0[4*a4+1]*inv);
    v0.z = f2bf(o0[4*a4+2]*inv); v0.w = f2bf(o0[4*a4+3]*inv);
    v1.x = f2bf(o1[4*a4+0]*inv); v1.y = f2bf(o1[4*a4+1]*inv);
    v1.z = f2bf(o1[4*a4+2]*inv); v1.w = f2bf(o1[4*a4+3]*inv);
    *reinterpret_cast<ushort4*>(op + 8*a4 + 4*hi)      = v0;
    *reinterpret_cast<ushort4*>(op + 32 + 8*a4 + 4*hi) = v1;
  }
}

// ---------------- launcher ----------------
extern "C" void kernel_launch(void* const* d_in, const int* in_sizes, int n_in,
                              void* d_out, int out_size, void* d_ws, size_t ws_size,
                              hipStream_t stream)
{
  (void)in_sizes; (void)n_in; (void)out_size;
  const float* Z  = (const float*)d_in[0];
  const float* Wq = (const float*)d_in[1];
  const float* bq = (const float*)d_in[2];
  const float* Wk = (const float*)d_in[3];
  const float* bk = (const float*)d_in[4];
  const float* Wv = (const float*)d_in[5];
  const float* bv = (const float*)d_in[6];
  const float* Wo = (const float*)d_in[7];
  const float* bo = (const float*)d_in[8];
  float* out = (float*)d_out;

  const size_t needed = (size_t)(M_TOT*D_MODEL)*2*5 + (size_t)(D_MODEL*D_MODEL)*2*4;
  if (ws_size < needed) return;

  u16* Zb  = (u16*)d_ws;
  u16* Wqb = Zb  + (size_t)M_TOT*D_MODEL;
  u16* Wkb = Wqb + (size_t)D_MODEL*D_MODEL;
  u16* Wvb = Wkb + (size_t)D_MODEL*D_MODEL;
  u16* Wob = Wvb + (size_t)D_MODEL*D_MODEL;
  u16* Qb  = Wob + (size_t)D_MODEL*D_MODEL;
  u16* Kb  = Qb  + (size_t)M_TOT*D_MODEL;
  u16* Vt  = Kb  + (size_t)M_TOT*D_MODEL;   // [b*NH+h][HD][SEQ]
  u16* Ab  = Vt  + (size_t)M_TOT*D_MODEL;

  cvt_all<<<dim3(8192), 256, 0, stream>>>(Z, Wq, Wk, Wv, Wo, Zb, Wqb, Wkb, Wvb, Wob);

  const size_t lds_bytes = 131072;   // 128KB dynamic LDS

  // QKV projections (Q epilogue pre-scaled by log2e/sqrt(d); V written transposed)
  dim3 gproj(D_MODEL/256, M_TOT/256, 3);
  gemm256<0,1><<<gproj, 512, lds_bytes, stream>>>(Zb, Wqb, Wkb, Wvb, bq, bk, bv,
                                                  (void*)Qb, (void*)Kb, (void*)Vt,
                                                  QSCALE, 1.0f, 1.0f,
                                                  M_TOT, D_MODEL, D_MODEL);

  dim3 gattn(SEQ/128, NB*NH);
  attn32<<<gattn, 256, 0, stream>>>(Qb, Kb, Vt, Ab);

  dim3 gout(D_MODEL/256, M_TOT/256, 1);
  gemm256<1,0><<<gout, 512, lds_bytes, stream>>>(Ab, Wob, Wob, Wob, bo, bo, bo,
                                                 (void*)out, (void*)out, (void*)out,
                                                 1.0f, 1.0f, 1.0f,
                                                 M_TOT, D_MODEL, D_MODEL);
}

// Round 8
// 218.376 us; speedup vs baseline: 1.1324x; 1.1324x over previous
//
#include <hip/hip_runtime.h>
#include <hip/hip_bf16.h>
#include <stdint.h>

typedef unsigned short u16;
typedef __bf16 bf16x8 __attribute__((ext_vector_type(8)));
typedef float f32x4 __attribute__((ext_vector_type(4)));
typedef float f32x16 __attribute__((ext_vector_type(16)));

#define D_MODEL 1024
#define SEQ     2048
#define NB      2
#define NH      16
#define HD      64
#define M_TOT   (NB*SEQ)        // 4096
// attention scale folded with log2(e): scores come out in log2 domain
#define QSCALE  (0.125f * 1.44269504088896f)
#define DEFER_THR 8.0f          // log2-domain defer-max threshold (P <= 2^8)

__device__ __forceinline__ u16 f2bf(float f) {
  union { __bf16 b; u16 u; } cv; cv.b = (__bf16)f; return cv.u;
}
__device__ __forceinline__ float exp2_fast(float x) {
  return __builtin_amdgcn_exp2f(x);
}

// async global->LDS, 16B per lane. lds_dst must be wave-uniform (HW adds lane*16).
__device__ __forceinline__ void async_copy16(void* lds_dst, const void* gsrc) {
  __builtin_amdgcn_global_load_lds(
      (const __attribute__((address_space(1))) unsigned int*)gsrc,
      (__attribute__((address_space(3))) unsigned int*)lds_dst, 16, 0, 0);
}

// ---------------- fused f32 -> bf16 convert for Z + 4 weights ----------------
__global__ void cvt_all(const float* __restrict__ Z,  const float* __restrict__ Wq,
                        const float* __restrict__ Wk, const float* __restrict__ Wv,
                        const float* __restrict__ Wo,
                        u16* __restrict__ Zb,  u16* __restrict__ Wqb,
                        u16* __restrict__ Wkb, u16* __restrict__ Wvb,
                        u16* __restrict__ Wob)
{
  int i = blockIdx.x * 256 + threadIdx.x;    // 0 .. 2^21-1
  const float* src; u16* dst; int off;
  if (i < (1 << 20)) { src = Z; dst = Zb; off = i; }
  else {
    int j = i - (1 << 20);
    int seg = j >> 18; off = j & ((1 << 18) - 1);
    src = (seg == 0) ? Wq : (seg == 1) ? Wk : (seg == 2) ? Wv : Wo;
    dst = (seg == 0) ? Wqb : (seg == 1) ? Wkb : (seg == 2) ? Wvb : Wob;
  }
  float4 v = reinterpret_cast<const float4*>(src)[off];
  ushort4 o;
  o.x = f2bf(v.x); o.y = f2bf(v.y); o.z = f2bf(v.z); o.w = f2bf(v.w);
  reinterpret_cast<ushort4*>(dst)[off] = o;
}

// ---------------- 256x256 GEMM, 8-phase schedule ----------------
// 512 threads = 8 waves (2M x 4N), per-wave 128x64 output, BK=64, double-buffered.
// Per K-tile: 4 phases {stage 2 loads for t+1 | barrier | ds_read subtile |
// lgkmcnt(0) | setprio(1) 16 MFMA setprio(0)}; vmcnt(0) drain once per tile at p0
// (every tile-t load issued 1-4 phases earlier). Stage order B0B1|B2B3|A0A1|A2A3.
// LDS slot swizzle (proven r7): LDS[row][sl] holds global k-chunk sl ^ (row&7).
// T1: XCD-swizzled (bx,by). TRANSV && z==2: swapped-operand MFMA, writes
// Vt[(b*NH+h)*HD+d][s] coalesced.
template<int F32OUT, int TRANSV>
__global__ __launch_bounds__(512, 2)
void gemm256(const u16* __restrict__ A,
             const u16* __restrict__ B0, const u16* __restrict__ B1, const u16* __restrict__ B2,
             const float* __restrict__ bias0, const float* __restrict__ bias1, const float* __restrict__ bias2,
             void* __restrict__ C0, void* __restrict__ C1, void* __restrict__ C2,
             float s0f, float s1f, float s2f,
             int M, int N, int K)
{
  (void)M;
  const int z = blockIdx.z;
  const u16* Bt = (z == 0) ? B0 : ((z == 1) ? B1 : B2);
  const float* bias = (z == 0) ? bias0 : ((z == 1) ? bias1 : bias2);
  void* Cout = (z == 0) ? C0 : ((z == 1) ? C1 : C2);
  const float oscl = (z == 0) ? s0f : ((z == 1) ? s1f : s2f);
  const bool vswap = TRANSV && (z == 2);

  extern __shared__ u16 smem[];          // A: 2x32KB, B: 2x32KB
  char* La = (char*)smem;
  char* Lb = (char*)smem + 65536;

  const int tid = threadIdx.x;
  const int w = tid >> 6, lane = tid & 63;
  const int l15 = lane & 15, lhi = lane >> 4;

  // T1: XCD-aware swizzle of the per-z 2D grid (gx*gy = 64, divisible by 8)
  int id = blockIdx.x + gridDim.x * blockIdx.y;
  const int n2 = gridDim.x * gridDim.y;
  id = (id & 7) * (n2 >> 3) + (id >> 3);
  const int bx = id % gridDim.x, by = id / gridDim.x;
  const int m0 = by * 256, n0 = bx * 256;
  const int wm = w >> 2, wn = w & 3;     // 2 x 4 wave grid

  f32x4 acc[8][4] = {};                  // 128 VGPRs

  // staging offsets (elements): chunk c = i*512+tid, row = c>>3, slot = c&7
  int aoff[4], boff[4];
  #pragma unroll
  for (int i = 0; i < 4; ++i) {
    const int c = i*512 + tid;
    const int row = c >> 3;
    const int sl  = c & 7;
    const int sg  = sl ^ (row & 7);      // inverse-swizzled global k-chunk
    aoff[i] = (m0 + row) * K + sg*8;
    boff[i] = (n0 + row) * K + sg*8;
  }
  int ldsoff[4];
  #pragma unroll
  for (int i = 0; i < 4; ++i) ldsoff[i] = (i*512 + w*64)*16;

  // stage pair j for tile kt into buffer buf: j=0:B01 j=1:B23 j=2:A01 j=3:A23
  auto stage_pair = [&](int j, int buf, int kt) {
    const int ko = kt << 6;
    const int bb = buf * 32768;
    if (j == 0) {
      async_copy16(Lb + bb + ldsoff[0], Bt + (size_t)(boff[0] + ko));
      async_copy16(Lb + bb + ldsoff[1], Bt + (size_t)(boff[1] + ko));
    } else if (j == 1) {
      async_copy16(Lb + bb + ldsoff[2], Bt + (size_t)(boff[2] + ko));
      async_copy16(Lb + bb + ldsoff[3], Bt + (size_t)(boff[3] + ko));
    } else if (j == 2) {
      async_copy16(La + bb + ldsoff[0], A + (size_t)(aoff[0] + ko));
      async_copy16(La + bb + ldsoff[1], A + (size_t)(aoff[1] + ko));
    } else {
      async_copy16(La + bb + ldsoff[2], A + (size_t)(aoff[2] + ko));
      async_copy16(La + bb + ldsoff[3], A + (size_t)(aoff[3] + ko));
    }
  };

  const int sl0 = lhi ^ (l15 & 7);                      // read slot, ks=0
  const int abase = (wm*128 + l15)*128 + sl0*16;        // byte in A-buf
  const int bbase = (wn*64  + l15)*128 + sl0*16;        // byte in B-buf

  const int nt = K >> 6;                 // 16 K-tiles

  // prologue: tile 0 fully staged into buf 0
  #pragma unroll
  for (int j = 0; j < 4; ++j) stage_pair(j, 0, 0);

  int cur = 0;
  for (int t = 0; t < nt; ++t) {
    const int bb = cur * 32768;
    const bool pf = (t + 1 < nt);
    bf16x8 Bf[4][2];                     // held through the tile (32 VGPR)

    #pragma unroll
    for (int q = 0; q < 4; ++q) {
      if (q == 0) {
        asm volatile("s_waitcnt vmcnt(0)" ::: "memory");   // tile-t loads landed
        __builtin_amdgcn_sched_barrier(0);
        __builtin_amdgcn_s_barrier();                      // visible to all waves
        __builtin_amdgcn_sched_barrier(0);
      } else {
        __builtin_amdgcn_s_barrier();                      // phase alignment
        __builtin_amdgcn_sched_barrier(0);
      }
      if (pf) stage_pair(q, cur ^ 1, t + 1);               // 2 loads / phase

      if (q == 0) {
        #pragma unroll
        for (int ni = 0; ni < 4; ++ni)
          #pragma unroll
          for (int ks = 0; ks < 2; ++ks)
            Bf[ni][ks] = *reinterpret_cast<const bf16x8*>(Lb + bb + ((bbase + ni*2048) ^ (ks << 6)));
      }
      bf16x8 Af[2][2];
      #pragma unroll
      for (int mm = 0; mm < 2; ++mm)
        #pragma unroll
        for (int ks = 0; ks < 2; ++ks)
          Af[mm][ks] = *reinterpret_cast<const bf16x8*>(La + bb + ((abase + (q*2+mm)*2048) ^ (ks << 6)));

      asm volatile("s_waitcnt lgkmcnt(0)" ::: "memory");
      __builtin_amdgcn_sched_barrier(0);
      __builtin_amdgcn_s_setprio(1);
      #pragma unroll
      for (int ks = 0; ks < 2; ++ks)
        #pragma unroll
        for (int mm = 0; mm < 2; ++mm) {
          const int mi = q*2 + mm;
          if (vswap) {
            #pragma unroll
            for (int ni = 0; ni < 4; ++ni)
              acc[mi][ni] = __builtin_amdgcn_mfma_f32_16x16x32_bf16(Bf[ni][ks], Af[mm][ks], acc[mi][ni], 0, 0, 0);
          } else {
            #pragma unroll
            for (int ni = 0; ni < 4; ++ni)
              acc[mi][ni] = __builtin_amdgcn_mfma_f32_16x16x32_bf16(Af[mm][ks], Bf[ni][ks], acc[mi][ni], 0, 0, 0);
          }
        }
      __builtin_amdgcn_s_setprio(0);
      __builtin_amdgcn_sched_barrier(0);
    }
    cur ^= 1;
  }

  if (vswap) {
    // acc[mi][ni] = C^T frag: d = n0+wn*64+ni*16+lhi*4+r, s = m0+wm*128+mi*16+l15
    #pragma unroll
    for (int mi = 0; mi < 8; ++mi) {
      const int sglob = m0 + wm*128 + mi*16 + l15;
      const int b2 = sglob >> 11, s = sglob & (SEQ - 1);
      #pragma unroll
      for (int ni = 0; ni < 4; ++ni) {
        #pragma unroll
        for (int r = 0; r < 4; ++r) {
          const int dglob = n0 + wn*64 + ni*16 + (lhi << 2) + r;
          const int hh = dglob >> 6, dd = dglob & 63;
          const float v = acc[mi][ni][r] + bias[dglob];
          reinterpret_cast<u16*>(Cout)[((size_t)(b2*NH + hh)*HD + dd)*SEQ + s] = f2bf(v);
        }
      }
    }
  } else {
    // C/D layout col=lane&15, row=(lane>>4)*4+reg
    #pragma unroll
    for (int mi = 0; mi < 8; ++mi) {
      const int rowb = m0 + wm*128 + mi*16 + (lhi << 2);
      #pragma unroll
      for (int ni = 0; ni < 4; ++ni) {
        const int col = n0 + wn*64 + ni*16 + l15;
        const float bb2 = bias[col];
        #pragma unroll
        for (int r = 0; r < 4; ++r) {
          const float v = (acc[mi][ni][r] + bb2) * oscl;
          if (F32OUT)
            reinterpret_cast<float*>(Cout)[(size_t)(rowb + r) * N + col] = v;
          else
            reinterpret_cast<u16*>(Cout)[(size_t)(rowb + r) * N + col] = f2bf(v);
        }
      }
    }
  }
}

// ---------------- fused flash attention, swapped 32x32 structure ----------------
// (unchanged — proven)
__global__ __launch_bounds__(256, 2)
void attn32(const u16* __restrict__ Qb, const u16* __restrict__ Kb,
            const u16* __restrict__ Vt, u16* __restrict__ Ob)
{
  __shared__ u16 vt[3][64*64];   // [d][8 slots of 8 keys]
  __shared__ u16 kt[3][64*64];   // [key][8 slots of 8 d]

  const int tid = threadIdx.x;
  const int w = tid >> 6, lane = tid & 63;
  const int l31 = lane & 31, hi = lane >> 5;
  const int bh = blockIdx.y, b = bh >> 4, h = bh & 15;
  const int qrow = blockIdx.x * 128 + w * 32 + l31;

  bf16x8 qf[4];
  {
    const u16* qp = Qb + (size_t)(b*SEQ + qrow) * D_MODEL + h*HD + hi*8;
    #pragma unroll
    for (int kc = 0; kc < 4; ++kc)
      qf[kc] = *reinterpret_cast<const bf16x8*>(qp + kc*16);
  }

  const u16* Vtg = Vt + (size_t)bh * HD * SEQ;            // [64 d][2048 s]
  const u16* Kg  = Kb + (size_t)(b*SEQ) * D_MODEL + h*HD; // rows [s][64 d]

  float mrun = -1e30f, lrun = 0.f;
  f32x16 o0 = {}, o1 = {};

  auto stageKV = [&](int buf, int kv0) {
    #pragma unroll
    for (int i = 0; i < 2; ++i) {
      const int c = i*256 + tid;
      const int d = c >> 3;
      const int sl = c & 7;
      const int sg = sl ^ (d & 7);
      async_copy16((char*)vt[buf] + (size_t)(i*256 + w*64)*16,
                   (const char*)(Vtg + (size_t)d*SEQ + kv0 + sg*8));
    }
    #pragma unroll
    for (int i = 0; i < 2; ++i) {
      const int c = i*256 + tid;
      const int key = c >> 3;
      const int sl = c & 7;
      const int sg = sl ^ (key & 7);
      async_copy16((char*)kt[buf] + (size_t)(i*256 + w*64)*16,
                   (const char*)(Kg + (size_t)(kv0 + key)*D_MODEL + sg*8));
    }
  };

  const int nt = SEQ / 64;   // 32 tiles
  stageKV(0, 0);
  stageKV(1, 64);

  for (int t = 0; t < nt; ++t) {
    const int cb = t % 3;
    if (t + 2 < nt) stageKV((t + 2) % 3, (t + 2) * 64);
    if (t + 2 < nt)      { asm volatile("s_waitcnt vmcnt(8)" ::: "memory"); }
    else if (t + 1 < nt) { asm volatile("s_waitcnt vmcnt(4)" ::: "memory"); }
    else                 { asm volatile("s_waitcnt vmcnt(0)" ::: "memory"); }
    __builtin_amdgcn_sched_barrier(0);
    __builtin_amdgcn_s_barrier();
    __builtin_amdgcn_sched_barrier(0);

    f32x16 s0 = {}, s1 = {};
    {
      const char* kbp = (const char*)kt[cb];
      #pragma unroll
      for (int kc = 0; kc < 4; ++kc) {
        const int sw = (kc*2 + hi) ^ (l31 & 7);
        bf16x8 ka0 = *reinterpret_cast<const bf16x8*>(kbp + (size_t)(l31*8 + sw)*16);
        s0 = __builtin_amdgcn_mfma_f32_32x32x16_bf16(ka0, qf[kc], s0, 0, 0, 0);
        bf16x8 ka1 = *reinterpret_cast<const bf16x8*>(kbp + (size_t)((l31+32)*8 + sw)*16);
        s1 = __builtin_amdgcn_mfma_f32_32x32x16_bf16(ka1, qf[kc], s1, 0, 0, 0);
      }
    }

    float tmax = s0[0];
    #pragma unroll
    for (int r = 1; r < 16; ++r) tmax = fmaxf(tmax, s0[r]);
    #pragma unroll
    for (int r = 0; r < 16; ++r) tmax = fmaxf(tmax, s1[r]);
    tmax = fmaxf(tmax, __shfl_xor(tmax, 32));
    if (!__all(tmax - mrun <= DEFER_THR)) {
      const float mnew = fmaxf(mrun, tmax);
      const float a = exp2_fast(mrun - mnew);
      lrun *= a;
      #pragma unroll
      for (int r = 0; r < 16; ++r) { o0[r] *= a; o1[r] *= a; }
      mrun = mnew;
    }
    float rs = 0.f;
    #pragma unroll
    for (int r = 0; r < 16; ++r) { s0[r] = exp2_fast(s0[r] - mrun); rs += s0[r]; }
    #pragma unroll
    for (int r = 0; r < 16; ++r) { s1[r] = exp2_fast(s1[r] - mrun); rs += s1[r]; }
    rs += __shfl_xor(rs, 32);
    lrun += rs;

    unsigned pwA[2][8];
    #pragma unroll
    for (int a4 = 0; a4 < 4; ++a4)
      #pragma unroll
      for (int zz = 0; zz < 2; ++zz) {
        pwA[0][a4*2+zz] = (unsigned)f2bf(s0[4*a4+2*zz]) | ((unsigned)f2bf(s0[4*a4+2*zz+1]) << 16);
        pwA[1][a4*2+zz] = (unsigned)f2bf(s1[4*a4+2*zz]) | ((unsigned)f2bf(s1[4*a4+2*zz+1]) << 16);
      }

    const char* vb = (const char*)vt[cb];
    #pragma unroll
    for (int ks = 0; ks < 4; ++ks) {
      const int kb = ks >> 1, sm = ks & 1;
      unsigned keep0 = hi ? pwA[kb][(2*sm+1)*2+0] : pwA[kb][(2*sm)*2+0];
      unsigned keep1 = hi ? pwA[kb][(2*sm+1)*2+1] : pwA[kb][(2*sm)*2+1];
      unsigned send0 = hi ? pwA[kb][(2*sm)*2+0]   : pwA[kb][(2*sm+1)*2+0];
      unsigned send1 = hi ? pwA[kb][(2*sm)*2+1]   : pwA[kb][(2*sm+1)*2+1];
      unsigned recv0 = (unsigned)__shfl_xor((int)send0, 32);
      unsigned recv1 = (unsigned)__shfl_xor((int)send1, 32);
      union { bf16x8 f; unsigned u[4]; } pf;
      pf.u[0] = hi ? recv0 : keep0;
      pf.u[1] = hi ? recv1 : keep1;
      pf.u[2] = hi ? keep0 : recv0;
      pf.u[3] = hi ? keep1 : recv1;

      const int slg = ks*2 + hi;
      const int sw  = slg ^ (l31 & 7);
      bf16x8 va0 = *reinterpret_cast<const bf16x8*>(vb + (size_t)(l31*8 + sw)*16);
      bf16x8 va1 = *reinterpret_cast<const bf16x8*>(vb + (size_t)((l31+32)*8 + sw)*16);

      o0 = __builtin_amdgcn_mfma_f32_32x32x16_bf16(va0, pf.f, o0, 0, 0, 0);
      o1 = __builtin_amdgcn_mfma_f32_32x32x16_bf16(va1, pf.f, o1, 0, 0, 0);
    }

    __builtin_amdgcn_sched_barrier(0);
    __builtin_amdgcn_s_barrier();
  }

  const float inv = 1.0f / lrun;
  u16* op = Ob + (size_t)(b*SEQ + qrow) * D_MODEL + h*HD;
  #pragma unroll
  for (int a4 = 0; a4 < 4; ++a4) {
    ushort4 v0, v1;
    v0.x = f2bf(o0[4*a4+0]*inv); v0.y = f2bf(o0[4*a4+1]*inv);
    v0.z = f2bf(o0[4*a4+2]*inv); v0.w = f2bf(o0[4*a4+3]*inv);
    v1.x = f2bf(o1[4*a4+0]*inv); v1.y = f2bf(o1[4*a4+1]*inv);
    v1.z = f2bf(o1[4*a4+2]*inv); v1.w = f2bf(o1[4*a4+3]*inv);
    *reinterpret_cast<ushort4*>(op + 8*a4 + 4*hi)      = v0;
    *reinterpret_cast<ushort4*>(op + 32 + 8*a4 + 4*hi) = v1;
  }
}

// ---------------- launcher ----------------
extern "C" void kernel_launch(void* const* d_in, const int* in_sizes, int n_in,
                              void* d_out, int out_size, void* d_ws, size_t ws_size,
                              hipStream_t stream)
{
  (void)in_sizes; (void)n_in; (void)out_size;
  const float* Z  = (const float*)d_in[0];
  const float* Wq = (const float*)d_in[1];
  const float* bq = (const float*)d_in[2];
  const float* Wk = (const float*)d_in[3];
  const float* bk = (const float*)d_in[4];
  const float* Wv = (const float*)d_in[5];
  const float* bv = (const float*)d_in[6];
  const float* Wo = (const float*)d_in[7];
  const float* bo = (const float*)d_in[8];
  float* out = (float*)d_out;

  const size_t needed = (size_t)(M_TOT*D_MODEL)*2*5 + (size_t)(D_MODEL*D_MODEL)*2*4;
  if (ws_size < needed) return;

  u16* Zb  = (u16*)d_ws;
  u16* Wqb = Zb  + (size_t)M_TOT*D_MODEL;
  u16* Wkb = Wqb + (size_t)D_MODEL*D_MODEL;
  u16* Wvb = Wkb + (size_t)D_MODEL*D_MODEL;
  u16* Wob = Wvb + (size_t)D_MODEL*D_MODEL;
  u16* Qb  = Wob + (size_t)D_MODEL*D_MODEL;
  u16* Kb  = Qb  + (size_t)M_TOT*D_MODEL;
  u16* Vt  = Kb  + (size_t)M_TOT*D_MODEL;   // [b*NH+h][HD][SEQ]
  u16* Ab  = Vt  + (size_t)M_TOT*D_MODEL;

  cvt_all<<<dim3(8192), 256, 0, stream>>>(Z, Wq, Wk, Wv, Wo, Zb, Wqb, Wkb, Wvb, Wob);

  const size_t lds_bytes = 131072;   // 128KB dynamic LDS

  // QKV projections (Q epilogue pre-scaled by log2e/sqrt(d); V written transposed)
  dim3 gproj(D_MODEL/256, M_TOT/256, 3);
  gemm256<0,1><<<gproj, 512, lds_bytes, stream>>>(Zb, Wqb, Wkb, Wvb, bq, bk, bv,
                                                  (void*)Qb, (void*)Kb, (void*)Vt,
                                                  QSCALE, 1.0f, 1.0f,
                                                  M_TOT, D_MODEL, D_MODEL);

  dim3 gattn(SEQ/128, NB*NH);
  attn32<<<gattn, 256, 0, stream>>>(Qb, Kb, Vt, Ab);

  dim3 gout(D_MODEL/256, M_TOT/256, 1);
  gemm256<1,0><<<gout, 512, lds_bytes, stream>>>(Ab, Wob, Wob, Wob, bo, bo, bo,
                                                 (void*)out, (void*)out, (void*)out,
                                                 1.0f, 1.0f, 1.0f,
                                                 M_TOT, D_MODEL, D_MODEL);
}